// Round 7
// baseline (182.698 us; speedup 1.0000x reference)
//
#include <hip/hip_runtime.h>

#define NQ 256
#define MK 1024
#define DD 512
#define CSC 2.8853900817779268f   // 2*log2(e): tanh(x) = 1 - 2/(exp2(CSC*x)+1)

// ---------------------------------------------------------------------------
// K1: all three projections, ONE dispatch, K-split x2 for occupancy.
//   u = blockIdx.x; kb = u&1 selects K-half [kb*256, kb*256+256).
//   Partial results combined via atomicAdd into zeroed buffers.
//   mode 0: qs  += CSC*(q @ WQ.T [+ bQ if kb==0])     [256 x 512]
//   mode 1: kts += CSC*(k @ WK.T [+ bK]) TRANSPOSED   [512 x 1024] (kts[d][m])
//   mode 2: vp  +=      v @ WV.T [+ bV]               [1024 x 512]
// 64x64 tile, 256 thr, 4x4 thread-tile, reg-double-buffered k-chunk 16.
// ---------------------------------------------------------------------------
__global__ __launch_bounds__(256) void proj_all(
    const float* __restrict__ q, const float* __restrict__ k, const float* __restrict__ v,
    const float* __restrict__ WQ, const float* __restrict__ bQ,
    const float* __restrict__ WK, const float* __restrict__ bK,
    const float* __restrict__ WV, const float* __restrict__ bV,
    float* __restrict__ qs, float* __restrict__ kts, float* __restrict__ vp)
{
    const int u = blockIdx.x;
    const int kb = u & 1;
    int t = u >> 1;
    const float *X, *W, *b;
    int mode, i0, j0;
    if (t < 32)       { mode = 0; X = q; W = WQ; b = bQ; }
    else if (t < 160) { mode = 1; t -= 32;  X = k; W = WK; b = bK; }
    else              { mode = 2; t -= 160; X = v; W = WV; b = bV; }
    i0 = (t >> 3) * 64;
    j0 = (t & 7) * 64;
    const int kbase = kb * 256;

    __shared__ float Xs[16][68];
    __shared__ float Ws[16][68];
    const int tid = threadIdx.x;
    const int tx = tid & 15, ty = tid >> 4;
    const int si = tid & 63;           // staging row
    const int sk = (tid >> 6) * 4;     // staging k-offset (float4 along k)

    float4 xa = *(const float4*)&X[(i0 + si) * DD + kbase + sk];
    float4 wa = *(const float4*)&W[(j0 + si) * DD + kbase + sk];

    float acc[4][4] = {};
    for (int k0 = kbase; k0 < kbase + 256; k0 += 16) {
        Xs[sk + 0][si] = xa.x; Xs[sk + 1][si] = xa.y; Xs[sk + 2][si] = xa.z; Xs[sk + 3][si] = xa.w;
        Ws[sk + 0][si] = wa.x; Ws[sk + 1][si] = wa.y; Ws[sk + 2][si] = wa.z; Ws[sk + 3][si] = wa.w;
        __syncthreads();
        if (k0 + 16 < kbase + 256) {
            xa = *(const float4*)&X[(i0 + si) * DD + k0 + 16 + sk];
            wa = *(const float4*)&W[(j0 + si) * DD + k0 + 16 + sk];
        }
#pragma unroll
        for (int kk = 0; kk < 16; ++kk) {
            float4 a4 = *(const float4*)&Xs[kk][ty * 4];
            float4 w4 = *(const float4*)&Ws[kk][tx * 4];
            float av[4] = {a4.x, a4.y, a4.z, a4.w};
            float wv[4] = {w4.x, w4.y, w4.z, w4.w};
#pragma unroll
            for (int r = 0; r < 4; ++r)
#pragma unroll
                for (int c = 0; c < 4; ++c)
                    acc[r][c] = fmaf(av[r], wv[c], acc[r][c]);
        }
        __syncthreads();
    }

    float4 bias = *(const float4*)&b[j0 + tx * 4];
    const float bs = (kb == 0) ? 1.0f : 0.0f;      // bias only once
    float bv[4] = {bias.x * bs, bias.y * bs, bias.z * bs, bias.w * bs};

    if (mode == 1) {
        // transposed, scaled: kts[j][i]
#pragma unroll
        for (int c = 0; c < 4; ++c)
#pragma unroll
            for (int r = 0; r < 4; ++r)
                atomicAdd(&kts[(j0 + tx * 4 + c) * MK + i0 + ty * 4 + r],
                          (acc[r][c] + bv[c]) * CSC);
    } else {
        float* dst = (mode == 0) ? qs : vp;
        const float sc = (mode == 0) ? CSC : 1.0f;
#pragma unroll
        for (int r = 0; r < 4; ++r)
#pragma unroll
            for (int c = 0; c < 4; ++c)
                atomicAdd(&dst[(i0 + ty * 4 + r) * DD + j0 + tx * 4 + c],
                          (acc[r][c] + bv[c]) * sc);
    }
}

// ---------------------------------------------------------------------------
// K2: scores. Lane = key (no cross-lane reduce). Block: 4 waves x 128-d-slice,
// 64 keys x SNG queries. qs/Ww chunk-preloaded into registers; kv dbuf.
//   S[n][m] = (sum(Ww)+bw) - 2 * sum_d Ww[d]*rcp(exp2(qs[n,d]+kts[d,m])+1)
// ---------------------------------------------------------------------------
#define SNG 4

__global__ __launch_bounds__(256) void score_v2(
    const float* __restrict__ qs, const float* __restrict__ kts,
    const float* __restrict__ Ww, const float* __restrict__ bw,
    const int* __restrict__ mask, float* __restrict__ S)
{
    const int lane = threadIdx.x & 63;
    const int wave = threadIdx.x >> 6;
    const int m = blockIdx.x * 64 + lane;
    const int n0 = blockIdx.y * SNG;
    const int d0 = wave * 128;

    __shared__ float part[4][SNG][64];

    float acc[SNG] = {0.f, 0.f, 0.f, 0.f};
    float kv[8], kvn[8];
#pragma unroll
    for (int j = 0; j < 8; ++j) kv[j] = kts[(d0 + j) * MK + m];

    for (int c = 0; c < 16; ++c) {
        const int d = d0 + c * 8;
        // chunk-preload of uniform operands (register-resident for 32 iters)
        float wwv[8], qv[SNG][8];
        {
            float4 w0 = *(const float4*)&Ww[d];
            float4 w1 = *(const float4*)&Ww[d + 4];
            wwv[0] = w0.x; wwv[1] = w0.y; wwv[2] = w0.z; wwv[3] = w0.w;
            wwv[4] = w1.x; wwv[5] = w1.y; wwv[6] = w1.z; wwv[7] = w1.w;
#pragma unroll
            for (int n = 0; n < SNG; ++n) {
                float4 a = *(const float4*)&qs[(n0 + n) * DD + d];
                float4 bq = *(const float4*)&qs[(n0 + n) * DD + d + 4];
                qv[n][0] = a.x;  qv[n][1] = a.y;  qv[n][2] = a.z;  qv[n][3] = a.w;
                qv[n][4] = bq.x; qv[n][5] = bq.y; qv[n][6] = bq.z; qv[n][7] = bq.w;
            }
        }
        if (c + 1 < 16) {
#pragma unroll
            for (int j = 0; j < 8; ++j) kvn[j] = kts[(d + 8 + j) * MK + m];
        }
#pragma unroll
        for (int j = 0; j < 8; ++j) {
#pragma unroll
            for (int n = 0; n < SNG; ++n) {
                float x = qv[n][j] + kv[j];
                float e = __builtin_amdgcn_exp2f(x);
                float r = __builtin_amdgcn_rcpf(e + 1.0f);
                acc[n] = fmaf(wwv[j], r, acc[n]);
            }
        }
#pragma unroll
        for (int j = 0; j < 8; ++j) kv[j] = kvn[j];
    }

#pragma unroll
    for (int n = 0; n < SNG; ++n) part[wave][n][lane] = acc[n];
    __syncthreads();

    if (wave == 0) {
        // sww = sum(Ww) + bw, computed once per block (64-lane reduce)
        float4 wa = *(const float4*)&Ww[lane * 8];
        float4 wb = *(const float4*)&Ww[lane * 8 + 4];
        float s = wa.x + wa.y + wa.z + wa.w + wb.x + wb.y + wb.z + wb.w;
        for (int o = 32; o > 0; o >>= 1) s += __shfl_xor(s, o, 64);
        const float cst = s + bw[0];
#pragma unroll
        for (int n = 0; n < SNG; ++n) {
            float p = part[0][n][lane] + part[1][n][lane]
                    + part[2][n][lane] + part[3][n][lane];
            float sc = fmaf(-2.0f, p, cst);
            sc = (mask[(n0 + n) * MK + m] == 1) ? sc : -1e6f;
            S[(n0 + n) * MK + m] = sc;
        }
    }
}

// ---------------------------------------------------------------------------
// K3: row softmax over m (1024) — one block per query row.
// ---------------------------------------------------------------------------
__global__ __launch_bounds__(256) void softmax_kernel(float* __restrict__ S)
{
    const int n = blockIdx.x;
    const int t = threadIdx.x;
    const int lane = t & 63, wave = t >> 6;
    __shared__ float red[4];

    float v[4];
    float mx = -3.4e38f;
#pragma unroll
    for (int i = 0; i < 4; ++i) {
        v[i] = S[n * MK + t + i * 256];
        mx = fmaxf(mx, v[i]);
    }
    for (int o = 32; o > 0; o >>= 1) mx = fmaxf(mx, __shfl_xor(mx, o, 64));
    if (lane == 0) red[wave] = mx;
    __syncthreads();
    mx = fmaxf(fmaxf(red[0], red[1]), fmaxf(red[2], red[3]));
    __syncthreads();

    float sum = 0.f;
#pragma unroll
    for (int i = 0; i < 4; ++i) {
        v[i] = __builtin_amdgcn_exp2f((v[i] - mx) * 1.4426950408889634f);
        sum += v[i];
    }
    for (int o = 32; o > 0; o >>= 1) sum += __shfl_xor(sum, o, 64);
    if (lane == 0) red[wave] = sum;
    __syncthreads();
    sum = red[0] + red[1] + red[2] + red[3];

    const float inv = __builtin_amdgcn_rcpf(sum);
#pragma unroll
    for (int i = 0; i < 4; ++i) S[n * MK + t + i * 256] = v[i] * inv;
}

// ---------------------------------------------------------------------------
// K4: context[n][d] = sum_m w[n][m]*vp[m][d]. 8 queries x 256-key chunk per
// block; weights in LDS [m][n] read as broadcast float4; atomics combine.
// ---------------------------------------------------------------------------
#define CNG 8
#define CMC 256

__global__ __launch_bounds__(512) void context_v2(const float* __restrict__ S,
                                                  const float* __restrict__ vp,
                                                  float* __restrict__ out)
{
    __shared__ float ws[CMC][12];   // [m][n], padded to 48B for aligned float4
    const int t = threadIdx.x;
    const int n0 = blockIdx.x * CNG;
    const int m0 = blockIdx.y * CMC;

#pragma unroll
    for (int p = 0; p < 4; ++p) {
        int e = t + p * 512;
        int m = e & 255, n = e >> 8;
        ws[m][n] = S[(n0 + n) * MK + m0 + m];
    }
    __syncthreads();

    float acc[CNG] = {};
    for (int m = 0; m < CMC; ++m) {
        float vv = vp[(m0 + m) * DD + t];
        float4 w0 = *(const float4*)&ws[m][0];
        float4 w4 = *(const float4*)&ws[m][4];
        acc[0] = fmaf(w0.x, vv, acc[0]);
        acc[1] = fmaf(w0.y, vv, acc[1]);
        acc[2] = fmaf(w0.z, vv, acc[2]);
        acc[3] = fmaf(w0.w, vv, acc[3]);
        acc[4] = fmaf(w4.x, vv, acc[4]);
        acc[5] = fmaf(w4.y, vv, acc[5]);
        acc[6] = fmaf(w4.z, vv, acc[6]);
        acc[7] = fmaf(w4.w, vv, acc[7]);
    }
#pragma unroll
    for (int n = 0; n < CNG; ++n) atomicAdd(&out[(n0 + n) * DD + t], acc[n]);
}

// ---------------------------------------------------------------------------
extern "C" void kernel_launch(void* const* d_in, const int* in_sizes, int n_in,
                              void* d_out, int out_size, void* d_ws, size_t ws_size,
                              hipStream_t stream)
{
    const float* q    = (const float*)d_in[0];
    const float* k    = (const float*)d_in[1];
    const float* v    = (const float*)d_in[2];
    const int*   mask = (const int*)  d_in[3];
    const float* WQ   = (const float*)d_in[4];
    const float* bQ   = (const float*)d_in[5];
    const float* WK   = (const float*)d_in[6];
    const float* bK   = (const float*)d_in[7];
    const float* WV   = (const float*)d_in[8];
    const float* bV   = (const float*)d_in[9];
    const float* Ww   = (const float*)d_in[10];
    const float* bw   = (const float*)d_in[11];
    float* out = (float*)d_out;

    float* qs  = (float*)d_ws;           // 256*512
    float* kts = qs + NQ * DD;           // 512*1024 (transposed, scaled)
    float* vp  = kts + DD * MK;          // 1024*512
    float* S   = vp + MK * DD;           // 256*1024

    // zero the atomic-accumulated buffers (qs..vp contiguous) and the output
    hipMemsetAsync(d_ws, 0, (size_t)(NQ * DD + DD * MK + MK * DD) * sizeof(float), stream);
    hipMemsetAsync(d_out, 0, (size_t)NQ * DD * sizeof(float), stream);

    proj_all<<<576, 256, 0, stream>>>(q, k, v, WQ, bQ, WK, bK, WV, bV, qs, kts, vp);

    score_v2<<<dim3(MK / 64, NQ / SNG), 256, 0, stream>>>(qs, kts, Ww, bw, mask, S);

    softmax_kernel<<<NQ, 256, 0, stream>>>(S);

    context_v2<<<dim3(NQ / CNG, MK / CMC), dim3(512), 0, stream>>>(S, vp, out);
}

// Round 8
// 175.624 us; speedup vs baseline: 1.0403x; 1.0403x over previous
//
#include <hip/hip_runtime.h>

#define NQ 256
#define MK 1024
#define DD 512
#define CSC 2.8853900817779268f   // 2*log2(e): tanh(x) = 1 - 2/(exp2(CSC*x)+1)

typedef __attribute__((ext_vector_type(8))) short short8;
typedef __attribute__((ext_vector_type(4))) float floatx4;

// ---------------------------------------------------------------------------
// K0: split f32 -> bf16 hi/lo pairs for q,k,v,WQ,WK,WV.
// One float4 per thread; region boundaries are block-uniform (all multiples
// of 256 float4s). 1920 blocks x 256.
// ---------------------------------------------------------------------------
__device__ inline void bsplit(float x, unsigned short& h, unsigned short& l)
{
    unsigned u = __float_as_uint(x);
    unsigned hr = (u + 0x7FFFu + ((u >> 16) & 1u)) >> 16;   // RN bf16
    h = (unsigned short)hr;
    float hf = __uint_as_float(hr << 16);
    unsigned ul = __float_as_uint(x - hf);
    l = (unsigned short)((ul + 0x7FFFu + ((ul >> 16) & 1u)) >> 16);
}

__global__ __launch_bounds__(256) void convert_split(
    const float* __restrict__ q, const float* __restrict__ k, const float* __restrict__ v,
    const float* __restrict__ WQ, const float* __restrict__ WK, const float* __restrict__ WV,
    unsigned short* __restrict__ qhi, unsigned short* __restrict__ qlo,
    unsigned short* __restrict__ khi, unsigned short* __restrict__ klo,
    unsigned short* __restrict__ vhi, unsigned short* __restrict__ vlo,
    unsigned short* __restrict__ wqhi, unsigned short* __restrict__ wqlo,
    unsigned short* __restrict__ wkhi, unsigned short* __restrict__ wklo,
    unsigned short* __restrict__ wvhi, unsigned short* __restrict__ wvlo)
{
    const int i = blockIdx.x * 256 + threadIdx.x;   // float4 index
    const float* src; unsigned short *dh, *dl; int li;
    if (i < 32768)       { src = q;  dh = qhi;  dl = qlo;  li = i; }
    else if (i < 163840) { src = k;  dh = khi;  dl = klo;  li = i - 32768; }
    else if (i < 294912) { src = v;  dh = vhi;  dl = vlo;  li = i - 163840; }
    else if (i < 360448) { src = WQ; dh = wqhi; dl = wqlo; li = i - 294912; }
    else if (i < 425984) { src = WK; dh = wkhi; dl = wklo; li = i - 360448; }
    else                 { src = WV; dh = wvhi; dl = wvlo; li = i - 425984; }

    float4 x = *(const float4*)&src[li * 4];
    ushort4 h, l;
    bsplit(x.x, h.x, l.x); bsplit(x.y, h.y, l.y);
    bsplit(x.z, h.z, l.z); bsplit(x.w, h.w, l.w);
    *(ushort4*)&dh[li * 4] = h;
    *(ushort4*)&dl[li * 4] = l;
}

// ---------------------------------------------------------------------------
// K1: projections via split-bf16 MFMA:  out = Xhi@Whi^T + Xhi@Wlo^T + Xlo@Whi^T
// Block: 256 thr = 4 waves; 64x64 output tile; wave w owns rows [w*16,w*16+16).
// mfma_f32_16x16x32_bf16: a/b frag = 8 contiguous bf16 at row (lane&15),
// k-slice (lane>>4)*8 (m92-verified pattern for B^T-stored GEMM);
// D: col=lane&15, row=(lane>>4)*4+reg (m89-verified).
//   mode 0: qs  = CSC*(q@WQ.T+bQ)            [256x512]
//   mode 1: kts = CSC*(k@WK.T+bK) TRANSPOSED [512x1024] (kts[d][m], float4 store)
//   mode 2: vp  = v@WV.T+bV                  [1024x512]
// ---------------------------------------------------------------------------
__global__ __launch_bounds__(256) void proj_mfma(
    const unsigned short* __restrict__ qhi, const unsigned short* __restrict__ qlo,
    const unsigned short* __restrict__ khi, const unsigned short* __restrict__ klo,
    const unsigned short* __restrict__ vhi, const unsigned short* __restrict__ vlo,
    const unsigned short* __restrict__ wqhi, const unsigned short* __restrict__ wqlo,
    const unsigned short* __restrict__ wkhi, const unsigned short* __restrict__ wklo,
    const unsigned short* __restrict__ wvhi, const unsigned short* __restrict__ wvlo,
    const float* __restrict__ bQ, const float* __restrict__ bK, const float* __restrict__ bV,
    float* __restrict__ qs, float* __restrict__ kts, float* __restrict__ vp)
{
    int t = blockIdx.x;
    const unsigned short *Xh, *Xl, *Wh, *Wl; const float* b; int mode;
    if (t < 32)       { mode = 0; Xh = qhi; Xl = qlo; Wh = wqhi; Wl = wqlo; b = bQ; }
    else if (t < 160) { mode = 1; t -= 32;  Xh = khi; Xl = klo; Wh = wkhi; Wl = wklo; b = bK; }
    else              { mode = 2; t -= 160; Xh = vhi; Xl = vlo; Wh = wvhi; Wl = wvlo; b = bV; }
    const int i0 = (t >> 3) * 64;
    const int j0 = (t & 7) * 64;

    const int l  = threadIdx.x & 63;
    const int w  = threadIdx.x >> 6;
    const int lr = l & 15;             // A-row / B-col / D-col within tile
    const int lk = (l >> 4) * 8;       // k-slice offset
    const int rbase = (l >> 4) * 4;    // D-row base

    const int arow = (i0 + w * 16 + lr) * DD;

    floatx4 acc[4] = {{0,0,0,0},{0,0,0,0},{0,0,0,0},{0,0,0,0}};

    for (int kk = 0; kk < DD; kk += 32) {
        short8 ah = *(const short8*)&Xh[arow + kk + lk];
        short8 al = *(const short8*)&Xl[arow + kk + lk];
#pragma unroll
        for (int nt = 0; nt < 4; ++nt) {
            const int brow = (j0 + nt * 16 + lr) * DD;
            short8 bh = *(const short8*)&Wh[brow + kk + lk];
            short8 bl = *(const short8*)&Wl[brow + kk + lk];
            acc[nt] = __builtin_amdgcn_mfma_f32_16x16x32_bf16(ah, bh, acc[nt], 0, 0, 0);
            acc[nt] = __builtin_amdgcn_mfma_f32_16x16x32_bf16(ah, bl, acc[nt], 0, 0, 0);
            acc[nt] = __builtin_amdgcn_mfma_f32_16x16x32_bf16(al, bh, acc[nt], 0, 0, 0);
        }
    }

    if (mode == 1) {
#pragma unroll
        for (int nt = 0; nt < 4; ++nt) {
            const float bb = b[j0 + nt * 16 + lr];
            float4 o;
            o.x = (acc[nt][0] + bb) * CSC;
            o.y = (acc[nt][1] + bb) * CSC;
            o.z = (acc[nt][2] + bb) * CSC;
            o.w = (acc[nt][3] + bb) * CSC;
            *(float4*)&kts[(j0 + nt * 16 + lr) * MK + i0 + w * 16 + rbase] = o;
        }
    } else {
        float* dst = (mode == 0) ? qs : vp;
        const float sc = (mode == 0) ? CSC : 1.0f;
#pragma unroll
        for (int nt = 0; nt < 4; ++nt) {
            const float bb = b[j0 + nt * 16 + lr];
#pragma unroll
            for (int j = 0; j < 4; ++j)
                dst[(i0 + w * 16 + rbase + j) * DD + j0 + nt * 16 + lr]
                    = (acc[nt][j] + bb) * sc;
        }
    }
}

// ---------------------------------------------------------------------------
// K2: scores. Lane = key (no cross-lane reduce). Block: 4 waves x 128-d-slice,
// 64 keys x SNG queries. qs/Ww chunk-preloaded into registers; kv dbuf.
//   S[n][m] = (sum(Ww)+bw) - 2 * sum_d Ww[d]*rcp(exp2(qs[n,d]+kts[d,m])+1)
// ---------------------------------------------------------------------------
#define SNG 4

__global__ __launch_bounds__(256) void score_v2(
    const float* __restrict__ qs, const float* __restrict__ kts,
    const float* __restrict__ Ww, const float* __restrict__ bw,
    const int* __restrict__ mask, float* __restrict__ S)
{
    const int lane = threadIdx.x & 63;
    const int wave = threadIdx.x >> 6;
    const int m = blockIdx.x * 64 + lane;
    const int n0 = blockIdx.y * SNG;
    const int d0 = wave * 128;

    __shared__ float part[4][SNG][64];

    float acc[SNG] = {0.f, 0.f, 0.f, 0.f};
    float kv[8], kvn[8];
#pragma unroll
    for (int j = 0; j < 8; ++j) kv[j] = kts[(d0 + j) * MK + m];

    for (int c = 0; c < 16; ++c) {
        const int d = d0 + c * 8;
        float wwv[8], qv[SNG][8];
        {
            float4 w0 = *(const float4*)&Ww[d];
            float4 w1 = *(const float4*)&Ww[d + 4];
            wwv[0] = w0.x; wwv[1] = w0.y; wwv[2] = w0.z; wwv[3] = w0.w;
            wwv[4] = w1.x; wwv[5] = w1.y; wwv[6] = w1.z; wwv[7] = w1.w;
#pragma unroll
            for (int n = 0; n < SNG; ++n) {
                float4 a = *(const float4*)&qs[(n0 + n) * DD + d];
                float4 bq = *(const float4*)&qs[(n0 + n) * DD + d + 4];
                qv[n][0] = a.x;  qv[n][1] = a.y;  qv[n][2] = a.z;  qv[n][3] = a.w;
                qv[n][4] = bq.x; qv[n][5] = bq.y; qv[n][6] = bq.z; qv[n][7] = bq.w;
            }
        }
        if (c + 1 < 16) {
#pragma unroll
            for (int j = 0; j < 8; ++j) kvn[j] = kts[(d + 8 + j) * MK + m];
        }
#pragma unroll
        for (int j = 0; j < 8; ++j) {
#pragma unroll
            for (int n = 0; n < SNG; ++n) {
                float x = qv[n][j] + kv[j];
                float e = __builtin_amdgcn_exp2f(x);
                float r = __builtin_amdgcn_rcpf(e + 1.0f);
                acc[n] = fmaf(wwv[j], r, acc[n]);
            }
        }
#pragma unroll
        for (int j = 0; j < 8; ++j) kv[j] = kvn[j];
    }

#pragma unroll
    for (int n = 0; n < SNG; ++n) part[wave][n][lane] = acc[n];
    __syncthreads();

    if (wave == 0) {
        float4 wa = *(const float4*)&Ww[lane * 8];
        float4 wb = *(const float4*)&Ww[lane * 8 + 4];
        float s = wa.x + wa.y + wa.z + wa.w + wb.x + wb.y + wb.z + wb.w;
        for (int o = 32; o > 0; o >>= 1) s += __shfl_xor(s, o, 64);
        const float cst = s + bw[0];
#pragma unroll
        for (int n = 0; n < SNG; ++n) {
            float p = part[0][n][lane] + part[1][n][lane]
                    + part[2][n][lane] + part[3][n][lane];
            float sc = fmaf(-2.0f, p, cst);
            sc = (mask[(n0 + n) * MK + m] == 1) ? sc : -1e6f;
            S[(n0 + n) * MK + m] = sc;
        }
    }
}

// ---------------------------------------------------------------------------
// K3: row softmax over m (1024) — one block per query row.
// ---------------------------------------------------------------------------
__global__ __launch_bounds__(256) void softmax_kernel(float* __restrict__ S)
{
    const int n = blockIdx.x;
    const int t = threadIdx.x;
    const int lane = t & 63, wave = t >> 6;
    __shared__ float red[4];

    float v[4];
    float mx = -3.4e38f;
#pragma unroll
    for (int i = 0; i < 4; ++i) {
        v[i] = S[n * MK + t + i * 256];
        mx = fmaxf(mx, v[i]);
    }
    for (int o = 32; o > 0; o >>= 1) mx = fmaxf(mx, __shfl_xor(mx, o, 64));
    if (lane == 0) red[wave] = mx;
    __syncthreads();
    mx = fmaxf(fmaxf(red[0], red[1]), fmaxf(red[2], red[3]));
    __syncthreads();

    float sum = 0.f;
#pragma unroll
    for (int i = 0; i < 4; ++i) {
        v[i] = __builtin_amdgcn_exp2f((v[i] - mx) * 1.4426950408889634f);
        sum += v[i];
    }
    for (int o = 32; o > 0; o >>= 1) sum += __shfl_xor(sum, o, 64);
    if (lane == 0) red[wave] = sum;
    __syncthreads();
    sum = red[0] + red[1] + red[2] + red[3];

    const float inv = __builtin_amdgcn_rcpf(sum);
#pragma unroll
    for (int i = 0; i < 4; ++i) S[n * MK + t + i * 256] = v[i] * inv;
}

// ---------------------------------------------------------------------------
// K4: context[n][d] = sum_m w[n][m]*vp[m][d]. 8 queries x 256-key chunk per
// block; weights in LDS [m][n] read as broadcast float4; atomics combine.
// ---------------------------------------------------------------------------
#define CNG 8
#define CMC 256

__global__ __launch_bounds__(512) void context_v2(const float* __restrict__ S,
                                                  const float* __restrict__ vp,
                                                  float* __restrict__ out)
{
    __shared__ float ws[CMC][12];   // [m][n], padded to 48B for aligned float4
    const int t = threadIdx.x;
    const int n0 = blockIdx.x * CNG;
    const int m0 = blockIdx.y * CMC;

#pragma unroll
    for (int p = 0; p < 4; ++p) {
        int e = t + p * 512;
        int m = e & 255, n = e >> 8;
        ws[m][n] = S[(n0 + n) * MK + m0 + m];
    }
    __syncthreads();

    float acc[CNG] = {};
    for (int m = 0; m < CMC; ++m) {
        float vv = vp[(m0 + m) * DD + t];
        float4 w0 = *(const float4*)&ws[m][0];
        float4 w4 = *(const float4*)&ws[m][4];
        acc[0] = fmaf(w0.x, vv, acc[0]);
        acc[1] = fmaf(w0.y, vv, acc[1]);
        acc[2] = fmaf(w0.z, vv, acc[2]);
        acc[3] = fmaf(w0.w, vv, acc[3]);
        acc[4] = fmaf(w4.x, vv, acc[4]);
        acc[5] = fmaf(w4.y, vv, acc[5]);
        acc[6] = fmaf(w4.z, vv, acc[6]);
        acc[7] = fmaf(w4.w, vv, acc[7]);
    }
#pragma unroll
    for (int n = 0; n < CNG; ++n) atomicAdd(&out[(n0 + n) * DD + t], acc[n]);
}

// ---------------------------------------------------------------------------
extern "C" void kernel_launch(void* const* d_in, const int* in_sizes, int n_in,
                              void* d_out, int out_size, void* d_ws, size_t ws_size,
                              hipStream_t stream)
{
    const float* q    = (const float*)d_in[0];
    const float* k    = (const float*)d_in[1];
    const float* v    = (const float*)d_in[2];
    const int*   mask = (const int*)  d_in[3];
    const float* WQ   = (const float*)d_in[4];
    const float* bQ   = (const float*)d_in[5];
    const float* WK   = (const float*)d_in[6];
    const float* bK   = (const float*)d_in[7];
    const float* WV   = (const float*)d_in[8];
    const float* bV   = (const float*)d_in[9];
    const float* Ww   = (const float*)d_in[10];
    const float* bw   = (const float*)d_in[11];
    float* out = (float*)d_out;

    // f32 workspace
    float* qs  = (float*)d_ws;           // 131072
    float* kts = qs + NQ * DD;           // 524288 (transposed, scaled)
    float* vp  = kts + DD * MK;          // 524288
    float* S   = vp + MK * DD;           // 262144
    // bf16 hi/lo workspace
    unsigned short* p16  = (unsigned short*)(S + NQ * MK);
    unsigned short* qhi  = p16;              p16 += NQ * DD;
    unsigned short* qlo  = p16;              p16 += NQ * DD;
    unsigned short* khi  = p16;              p16 += MK * DD;
    unsigned short* klo  = p16;              p16 += MK * DD;
    unsigned short* vhi  = p16;              p16 += MK * DD;
    unsigned short* vlo  = p16;              p16 += MK * DD;
    unsigned short* wqhi = p16;              p16 += DD * DD;
    unsigned short* wqlo = p16;              p16 += DD * DD;
    unsigned short* wkhi = p16;              p16 += DD * DD;
    unsigned short* wklo = p16;              p16 += DD * DD;
    unsigned short* wvhi = p16;              p16 += DD * DD;
    unsigned short* wvlo = p16;

    hipMemsetAsync(d_out, 0, (size_t)NQ * DD * sizeof(float), stream);

    convert_split<<<1920, 256, 0, stream>>>(q, k, v, WQ, WK, WV,
        qhi, qlo, khi, klo, vhi, vlo, wqhi, wqlo, wkhi, wklo, wvhi, wvlo);

    proj_mfma<<<288, 256, 0, stream>>>(qhi, qlo, khi, klo, vhi, vlo,
        wqhi, wqlo, wkhi, wklo, wvhi, wvlo, bQ, bK, bV, qs, kts, vp);

    score_v2<<<dim3(MK / 64, NQ / SNG), 256, 0, stream>>>(qs, kts, Ww, bw, mask, S);

    softmax_kernel<<<NQ, 256, 0, stream>>>(S);

    context_v2<<<dim3(NQ / CNG, MK / CMC), dim3(512), 0, stream>>>(S, vp, out);
}